// Round 10
// baseline (164.140 us; speedup 1.0000x reference)
//
#include <hip/hip_runtime.h>
#include <hip/hip_bf16.h>
#include <stdint.h>

#define HEAD 64
#define CEMB 1024
#define BB 8
#define TSEQ 2048

typedef __attribute__((ext_vector_type(8))) short bf16x8;
typedef __attribute__((ext_vector_type(4))) float f32x4;

__device__ __forceinline__ unsigned short f2bf(float f) {
    union { float f; uint32_t u; } c; c.f = f;
    uint32_t u = c.u + 0x7FFF + ((c.u >> 16) & 1);
    return (unsigned short)(u >> 16);
}
__device__ __forceinline__ bf16x8 f8bf(float4 a, float4 b) {
    unsigned short t[8];
    t[0] = f2bf(a.x); t[1] = f2bf(a.y); t[2] = f2bf(a.z); t[3] = f2bf(a.w);
    t[4] = f2bf(b.x); t[5] = f2bf(b.y); t[6] = f2bf(b.z); t[7] = f2bf(b.w);
    return *(bf16x8*)t;
}

// ---------------- Kernel 0: W -> WTf, MFMA-fragment order --------------------
// Fragment (kc, j): 64 lanes x 16B contiguous (1 KB); n = j*16+(lane&15),
// k = kc*32 + (lane>>4)*8 + e.  j: 0-3 K, 4-7 Q(scaled), 8-11 V.
__global__ __launch_bounds__(256) void prep_w(
        const float* __restrict__ Wk, const float* __restrict__ bk,
        const float* __restrict__ Wq, const float* __restrict__ bq,
        const float* __restrict__ Wv, const float* __restrict__ bv,
        unsigned short* __restrict__ WTf, float* __restrict__ biasb) {
    __shared__ float Wl[3][32][64];
    const int kc = blockIdx.x;               // 0..31
    const int tid = threadIdx.x;
    const float* Ws[3] = {Wk, Wq, Wv};
    const int row = tid >> 3, cf = (tid & 7) * 8;
    #pragma unroll
    for (int p = 0; p < 3; p++) {
        const float* W = Ws[p] + (long)(kc * 32 + row) * 64 + cf;
        float4 v0 = *(const float4*)(W);
        float4 v1 = *(const float4*)(W + 4);
        *(float4*)(&Wl[p][row][cf]) = v0;
        *(float4*)(&Wl[p][row][cf + 4]) = v1;
    }
    __syncthreads();
    #pragma unroll
    for (int i = 0; i < 3; i++) {
        int cid = i * 256 + tid;             // 0..767 = j*64 + lane
        int lane = cid & 63;
        int l15 = lane & 15, q4 = lane >> 4;
        int n = (cid >> 6) * 16 + l15;
        int p = n >> 6, col = n & 63;
        float scale = (p == 1) ? 0.03125f : 1.0f;   // fold C^-0.5 into q
        unsigned short o[8];
        for (int e = 0; e < 8; e++) o[e] = f2bf(Wl[p][q4 * 8 + e][col] * scale);
        *(int4*)(WTf + (long)kc * 6144 + (long)cid * 8) = *(int4*)o;
    }
    if (kc == 0 && tid < 192) {
        const float* bs[3] = {bk, bq, bv};
        int p = tid >> 6;
        biasb[tid] = bs[p][tid & 63] * ((p == 1) ? 0.03125f : 1.0f);
    }
}

// ---------------- Kernel 1: projections, no-LDS zero-barrier -----------------
// grid 512 x 384thr (6 waves). Wave = (m-half, n-group): 1 m-tile (16 rows) x
// 4 n-tiles. A fragments loaded DIRECTLY from global in MFMA-A layout (two
// float4/lane; rows L1/L2-hot, 3x shared), cvt in-register; B via coalesced
// 1KB fragment loads (L2-hot). 1-deep prefetch of A+B. NO LDS, NO BARRIERS:
// every prior proj (42-47us, all pipes <15%) shared LDS staging + K-loop
// __syncthreads; this removes both. ~80 VGPR; (384,3) -> 170 cap, no spill.
__global__ __launch_bounds__(384, 3) void proj_gemm(
        const float* __restrict__ x, const unsigned short* __restrict__ WTf,
        const float* __restrict__ biasb,
        unsigned short* __restrict__ Kb, unsigned short* __restrict__ Qb,
        unsigned short* __restrict__ VTb) {
    const int tid = threadIdx.x;
    const int lane = tid & 63, w = tid >> 6;     // 6 waves
    const int l15 = lane & 15, q4 = lane >> 4;
    const int mh = w & 1;                        // m-tile 0..1
    const int ng = w >> 1;                       // n-group 0..2 (4 n-tiles each)
    const long rowbase = (long)blockIdx.x * 32;

    const float* xr = x + (rowbase + mh * 16 + l15) * CEMB + q4 * 8;
    const unsigned short* Bg = WTf + (long)(ng * 4) * 512 + (long)lane * 8;

    f32x4 z = {0.f, 0.f, 0.f, 0.f};
    f32x4 acc[4];
    #pragma unroll
    for (int nt = 0; nt < 4; nt++) acc[nt] = z;

    // prefetch kg=0
    float4 a0 = *(const float4*)(xr);
    float4 a1 = *(const float4*)(xr + 4);
    bf16x8 bp[4];
    #pragma unroll
    for (int nt = 0; nt < 4; nt++)
        bp[nt] = *(const bf16x8*)(Bg + nt * 512);

    #pragma unroll
    for (int kg = 0; kg < 32; kg++) {
        float4 c0 = a0, c1 = a1;
        bf16x8 bc[4];
        #pragma unroll
        for (int nt = 0; nt < 4; nt++) bc[nt] = bp[nt];
        // issue next-iteration loads (stay in flight across cvt + MFMA)
        if (kg < 31) {
            a0 = *(const float4*)(xr + (kg + 1) * 32);
            a1 = *(const float4*)(xr + (kg + 1) * 32 + 4);
            #pragma unroll
            for (int nt = 0; nt < 4; nt++)
                bp[nt] = *(const bf16x8*)(Bg + (long)(kg + 1) * 6144 + nt * 512);
        }
        bf16x8 af = f8bf(c0, c1);
        #pragma unroll
        for (int nt = 0; nt < 4; nt++)
            acc[nt] = __builtin_amdgcn_mfma_f32_16x16x32_bf16(af, bc[nt], acc[nt], 0, 0, 0);
    }

    // ---- epilogue: +bias, cast bf16, per-wave scatter ----
    #pragma unroll
    for (int nt = 0; nt < 4; nt++) {
        const int n = (ng * 4 + nt) * 16 + l15;
        const float bias = biasb[n];
        const long row0 = rowbase + mh * 16 + q4 * 4;
        if (n < 128) {
            unsigned short* dst = (n < 64) ? (Kb + row0 * HEAD + n)
                                           : (Qb + row0 * HEAD + (n - 64));
            for (int r = 0; r < 4; r++)
                dst[r * HEAD] = f2bf(acc[nt][r] + bias);
        } else {
            const int h = n - 128;
            const long b = row0 >> 11; const int t = (int)(row0 & 2047);
            ushort4 pk;
            pk.x = f2bf(acc[nt][0] + bias);
            pk.y = f2bf(acc[nt][1] + bias);
            pk.z = f2bf(acc[nt][2] + bias);
            pk.w = f2bf(acc[nt][3] + bias);
            *(ushort4*)(VTb + b * (HEAD * (long)TSEQ) + (long)h * TSEQ + t) = pk;
        }
    }
}

// ---------------- Kernel 2: causal softplus-attention (R6 verbatim) ----------
// Default launch bounds; R8's (512,4) caused an 80 MB scratch spill.
__global__ __launch_bounds__(512) void attn(
        const unsigned short* __restrict__ Kb, const unsigned short* __restrict__ Qb,
        const unsigned short* __restrict__ VTb, float* __restrict__ out) {
    __shared__ __align__(16) char sm[36864];   // union: Pl 20480 | red 36864
    unsigned short* Pl = (unsigned short*)sm;  // [8 waves][32*40]
    float* red = (float*)sm;                   // [4][64*36]

    const int tid = threadIdx.x;
    const int lane = tid & 63, w = tid >> 6;   // 8 waves
    const int l15 = lane & 15, q4 = lane >> 4;

    const int bid = blockIdx.x;
    const int ti = 63 - (bid >> 3);            // largest t-tile first
    const int b = bid & 7;
    const int t0 = ti * 32;

    const unsigned short* kb  = Kb  + (long)b * TSEQ * HEAD;
    const unsigned short* qb  = Qb  + (long)b * TSEQ * HEAD;
    const unsigned short* vtb = VTb + (long)b * HEAD * TSEQ;

    bf16x8 kf[2][2];
    for (int tt = 0; tt < 2; tt++)
        for (int kk = 0; kk < 2; kk++)
            kf[tt][kk] = *(const bf16x8*)(kb + (t0 + tt * 16 + l15) * HEAD + kk * 32 + q4 * 8);

    f32x4 z = {0.f, 0.f, 0.f, 0.f};
    f32x4 oacc[4][2];
    for (int hh = 0; hh < 4; hh++) for (int tt = 0; tt < 2; tt++) oacc[hh][tt] = z;

    bf16x8 qpf[2][2], vpf[4];
    if (w <= ti) {
        const int s0 = w * 32;
        for (int st2 = 0; st2 < 2; st2++)
            for (int kk = 0; kk < 2; kk++)
                qpf[st2][kk] = *(const bf16x8*)(qb + (s0 + st2 * 16 + l15) * HEAD + kk * 32 + q4 * 8);
        for (int hh = 0; hh < 4; hh++)
            vpf[hh] = *(const bf16x8*)(vtb + (hh * 16 + l15) * (long)TSEQ + s0 + q4 * 8);
    }

    unsigned short* myP = Pl + w * 1280;
    for (int c = w; c <= ti; c += 8) {
        const int s0 = c * 32;

        bf16x8 qf[2][2], vf[4];
        for (int st2 = 0; st2 < 2; st2++)
            for (int kk = 0; kk < 2; kk++) qf[st2][kk] = qpf[st2][kk];
        for (int hh = 0; hh < 4; hh++) vf[hh] = vpf[hh];

        if (c + 8 <= ti) {
            const int sn = (c + 8) * 32;
            for (int st2 = 0; st2 < 2; st2++)
                for (int kk = 0; kk < 2; kk++)
                    qpf[st2][kk] = *(const bf16x8*)(qb + (sn + st2 * 16 + l15) * HEAD + kk * 32 + q4 * 8);
            for (int hh = 0; hh < 4; hh++)
                vpf[hh] = *(const bf16x8*)(vtb + (hh * 16 + l15) * (long)TSEQ + sn + q4 * 8);
        }

        // S^T = Q K^T: 2 s-tiles x 2 t-tiles
        f32x4 sc[2][2];
        for (int st2 = 0; st2 < 2; st2++)
            for (int tt = 0; tt < 2; tt++) {
                f32x4 s = z;
                s = __builtin_amdgcn_mfma_f32_16x16x32_bf16(qf[st2][0], kf[tt][0], s, 0, 0, 0);
                s = __builtin_amdgcn_mfma_f32_16x16x32_bf16(qf[st2][1], kf[tt][1], s, 0, 0, 0);
                sc[st2][tt] = s;
            }
        // softplus + causal mask; pack bf16 -> P^T LDS [t-local][s-local]
        for (int tt = 0; tt < 2; tt++) {
            const int tg = t0 + tt * 16 + l15;
            for (int st2 = 0; st2 < 2; st2++) {
                ushort4 pk;
                unsigned short pv[4];
                for (int r = 0; r < 4; r++) {
                    int sg = s0 + st2 * 16 + q4 * 4 + r;
                    float p = __logf(1.0f + __expf(sc[st2][tt][r]));
                    if (sg > tg) p = 0.0f;
                    pv[r] = f2bf(p);
                }
                pk.x = pv[0]; pk.y = pv[1]; pk.z = pv[2]; pk.w = pv[3];
                *(ushort4*)(myP + (tt * 16 + l15) * 40 + st2 * 16 + q4 * 4) = pk;
            }
        }
        __threadfence_block();
        bf16x8 pf0 = *(const bf16x8*)(myP + l15 * 40 + q4 * 8);
        bf16x8 pf1 = *(const bf16x8*)(myP + (16 + l15) * 40 + q4 * 8);
        for (int hh = 0; hh < 4; hh++) {
            oacc[hh][0] = __builtin_amdgcn_mfma_f32_16x16x32_bf16(vf[hh], pf0, oacc[hh][0], 0, 0, 0);
            oacc[hh][1] = __builtin_amdgcn_mfma_f32_16x16x32_bf16(vf[hh], pf1, oacc[hh][1], 0, 0, 0);
        }
    }

    // ---- 3-stage tree reduction over 8 waves (red unions Pl; synced) ----
    __syncthreads();                           // all Pl use done
    if (w >= 4) {
        float* r0 = red + (w - 4) * 2304 + lane * 36;
        for (int hh = 0; hh < 4; hh++)
            for (int tt = 0; tt < 2; tt++)
                *(f32x4*)(r0 + (hh * 2 + tt) * 4) = oacc[hh][tt];
    }
    __syncthreads();
    if (w < 4) {
        const float* r0 = red + w * 2304 + lane * 36;
        for (int hh = 0; hh < 4; hh++)
            for (int tt = 0; tt < 2; tt++)
                oacc[hh][tt] += *(const f32x4*)(r0 + (hh * 2 + tt) * 4);
    }
    __syncthreads();
    if (w == 2 || w == 3) {
        float* r0 = red + (w - 2) * 2304 + lane * 36;
        for (int hh = 0; hh < 4; hh++)
            for (int tt = 0; tt < 2; tt++)
                *(f32x4*)(r0 + (hh * 2 + tt) * 4) = oacc[hh][tt];
    }
    __syncthreads();
    if (w < 2) {
        const float* r0 = red + w * 2304 + lane * 36;
        for (int hh = 0; hh < 4; hh++)
            for (int tt = 0; tt < 2; tt++)
                oacc[hh][tt] += *(const f32x4*)(r0 + (hh * 2 + tt) * 4);
    }
    __syncthreads();
    if (w == 1) {
        float* r0 = red + lane * 36;
        for (int hh = 0; hh < 4; hh++)
            for (int tt = 0; tt < 2; tt++)
                *(f32x4*)(r0 + (hh * 2 + tt) * 4) = oacc[hh][tt];
    }
    __syncthreads();
    if (w == 0) {
        const float* r0 = red + lane * 36;
        for (int hh = 0; hh < 4; hh++)
            for (int tt = 0; tt < 2; tt++)
                oacc[hh][tt] += *(const f32x4*)(r0 + (hh * 2 + tt) * 4);
        for (int tt = 0; tt < 2; tt++) {
            float* ob = out + ((long)b * TSEQ + t0 + tt * 16 + l15) * HEAD + q4 * 4;
            for (int hh = 0; hh < 4; hh++)
                *(f32x4*)(ob + hh * 16) = oacc[hh][tt];
        }
    }
}

// ---------------- host launch ------------------------------------------------
extern "C" void kernel_launch(void* const* d_in, const int* in_sizes, int n_in,
                              void* d_out, int out_size, void* d_ws, size_t ws_size,
                              hipStream_t stream) {
    const float* x  = (const float*)d_in[0];
    const float* Wk = (const float*)d_in[1];
    const float* bk = (const float*)d_in[2];
    const float* Wq = (const float*)d_in[3];
    const float* bq = (const float*)d_in[4];
    const float* Wv = (const float*)d_in[5];
    const float* bv = (const float*)d_in[6];
    float* out = (float*)d_out;

    char* ws = (char*)d_ws;
    unsigned short* WTf   = (unsigned short*)(ws);                      // 384 KB
    float*          biasb = (float*)(ws + 393216);                      // 768 B
    unsigned short* Kb    = (unsigned short*)(ws + 524288);             // 2 MB
    unsigned short* Qb    = (unsigned short*)(ws + 524288 + 2097152);   // 2 MB
    unsigned short* VTb   = (unsigned short*)(ws + 524288 + 4194304);   // 2 MB

    prep_w<<<32, 256, 0, stream>>>(Wk, bk, Wq, bq, Wv, bv, WTf, biasb);
    proj_gemm<<<512, 384, 0, stream>>>(x, WTf, biasb, Kb, Qb, VTb);
    attn<<<512, 512, 0, stream>>>(Kb, Qb, VTb, out);
}